// Round 3
// baseline (510.957 us; speedup 1.0000x reference)
//
#include <hip/hip_runtime.h>
#include <hip/hip_bf16.h>

constexpr int V = 128;
constexpr int NTILES = 512;          // 8^3 tiles of 16^3
constexpr int TD = 17;               // tile cells per dim incl +1 halo
constexpr int TSIZE = TD * TD * TD;  // 4913
constexpr int TPAD = 5120;           // padded tile block (floats)
constexpr int CAP = 4096;            // bucket capacity per tile (mean ~980)

// ---------------- Kernel 1: partial[b][8] = chunk of coords_flat @ W0 ----------------
__global__ __launch_bounds__(256) void k_reduce_w0(
    const int* __restrict__ inds, const float* __restrict__ W0,
    float* __restrict__ partials, int threeN) {
  float acc[8];
#pragma unroll
  for (int k = 0; k < 8; ++k) acc[k] = 0.f;

  int stride = gridDim.x * blockDim.x;
  for (int j = blockIdx.x * blockDim.x + threadIdx.x; j < threeN; j += stride) {
    int c = j % 3;
    float cval = ((float)inds[j + 2 - 2 * c] - 64.0f) * 0.015625f;
    const float4* w = (const float4*)(W0 + (size_t)j * 8);
    float4 a = w[0];
    float4 b = w[1];
    acc[0] += cval * a.x; acc[1] += cval * a.y;
    acc[2] += cval * a.z; acc[3] += cval * a.w;
    acc[4] += cval * b.x; acc[5] += cval * b.y;
    acc[6] += cval * b.z; acc[7] += cval * b.w;
  }

#pragma unroll
  for (int off = 32; off > 0; off >>= 1) {
#pragma unroll
    for (int k = 0; k < 8; ++k) acc[k] += __shfl_down(acc[k], off);
  }

  __shared__ float red[4][8];
  int wave = threadIdx.x >> 6;
  int lane = threadIdx.x & 63;
  if (lane == 0) {
#pragma unroll
    for (int k = 0; k < 8; ++k) red[wave][k] = acc[k];
  }
  __syncthreads();
  if (threadIdx.x < 8) {
    int k = threadIdx.x;
    partials[(size_t)blockIdx.x * 8 + k] = red[0][k] + red[1][k] + red[2][k] + red[3][k];
  }
}

// ---------------- Kernel 2: reduce partials + tiny MLP ----------------
__global__ __launch_bounds__(256) void k_mlp(
    const float* __restrict__ partials, int nb,
    const float* __restrict__ b0,
    const float* __restrict__ W1, const float* __restrict__ b1,
    const float* __restrict__ W2, const float* __restrict__ b2,
    const float* __restrict__ W3, const float* __restrict__ b3,
    const float* __restrict__ W4, const float* __restrict__ b4,
    float* __restrict__ x8_out) {
  __shared__ float red[256];
  __shared__ float accv[8];
  int tid = threadIdx.x;
  int k = tid & 7;
  float s = 0.f;
  for (int b = tid >> 3; b < nb; b += 32) s += partials[(size_t)b * 8 + k];
  red[tid] = s;
  __syncthreads();
  if (tid < 8) {
    float t = 0.f;
    for (int j = tid; j < 256; j += 8) t += red[j];
    accv[tid] = t;
  }
  __syncthreads();
  if (tid == 0) {
    float x[8];
#pragma unroll
    for (int kk = 0; kk < 8; ++kk) x[kk] = sinf(accv[kk] + b0[kk]);
    const float* Ws[4] = {W1, W2, W3, W4};
    const float* bs[4] = {b1, b2, b3, b4};
    for (int l = 0; l < 4; ++l) {
      float t[8];
#pragma unroll
      for (int kk = 0; kk < 8; ++kk) {
        float ss = bs[l][kk];
#pragma unroll
        for (int j = 0; j < 8; ++j) ss += x[j] * Ws[l][j * 8 + kk];
        t[kk] = ss;
      }
#pragma unroll
      for (int kk = 0; kk < 8; ++kk) x[kk] += sinf(t[kk]);
    }
#pragma unroll
    for (int kk = 0; kk < 8; ++kk) x8_out[kk] = x[kk];
  }
}

__device__ inline int tile_of(float cx, float cy, float cz) {
  int bx = (int)floorf(cx), by = (int)floorf(cy), bz = (int)floorf(cz);
  int tx = min(max(bx, 0), V - 1) >> 4;
  int ty = min(max(by, 0), V - 1) >> 4;
  int tz = min(max(bz, 0), V - 1) >> 4;
  return (tz << 6) | (ty << 3) | tx;
}

// ---------------- A: decode + direct bucket scatter (single pass) ----------------
__global__ __launch_bounds__(256) void k_decode_scatter(
    const int* __restrict__ inds, const float* __restrict__ refv,
    const float* __restrict__ W5, const float* __restrict__ b5,
    const float* __restrict__ x8_buf, float4* __restrict__ srt,
    int* __restrict__ gcnt, int N) {
  __shared__ float x8[8];
  if (threadIdx.x < 8) x8[threadIdx.x] = x8_buf[threadIdx.x];
  __syncthreads();

  int i = blockIdx.x * 256 + threadIdx.x;
  if (i >= N) return;

  const size_t fourN = (size_t)4 * N;
  float4 o = *(const float4*)(b5 + (size_t)4 * i);
  float out0 = o.x, out1 = o.y, out2 = o.z, out3 = o.w;
#pragma unroll
  for (int k = 0; k < 8; ++k) {
    float xv = x8[k];
    float4 w = *(const float4*)(W5 + (size_t)k * fourN + (size_t)4 * i);
    out0 += xv * w.x; out1 += xv * w.y; out2 += xv * w.z; out3 += xv * w.w;
  }
  float value = refv[i] + out3;
  value = value > 0.f ? value : 0.f;
  if (value <= 0.f) return;  // zero value contributes nothing to any corner

  int i0 = inds[3 * i], i1 = inds[3 * i + 1], i2 = inds[3 * i + 2];
  float cx = (((float)i2 - 64.0f) * 0.015625f + out0) * 64.0f + 64.0f;
  float cy = (((float)i1 - 64.0f) * 0.015625f + out1) * 64.0f + 64.0f;
  float cz = (((float)i0 - 64.0f) * 0.015625f + out2) * 64.0f + 64.0f;

  int t = tile_of(cx, cy, cz);
  int pos = atomicAdd(&gcnt[t], 1);
  if (pos < CAP) srt[(size_t)t * CAP + pos] = make_float4(cx, cy, cz, value);
}

// ---------------- B: per-tile LDS scatter -> private tile blocks ----------------
__global__ __launch_bounds__(256) void k_tile(
    const float4* __restrict__ srt, const int* __restrict__ gcnt,
    float* __restrict__ priv, float* __restrict__ vol) {
  __shared__ float tl[TSIZE];
  int t = blockIdx.x;
  int ox = (t & 7) << 4, oy = ((t >> 3) & 7) << 4, oz = (t >> 6) << 4;
  for (int j = threadIdx.x; j < TSIZE; j += 256) tl[j] = 0.f;
  __syncthreads();

  int cnt = min(gcnt[t], CAP);
  const float4* base = srt + (size_t)t * CAP;
  for (int i = threadIdx.x; i < cnt; i += 256) {
    float4 r = base[i];
    float bxf = floorf(r.x), byf = floorf(r.y), bzf = floorf(r.z);
    int bx = (int)bxf, by = (int)byf, bz = (int)bzf;
    float fx = r.x - bxf, fy = r.y - byf, fz = r.z - bzf;
    float gx = 1.f - fx, gy = 1.f - fy, gz = 1.f - fz;
    float value = r.w;

#pragma unroll
    for (int dz = 0; dz < 2; ++dz) {
#pragma unroll
      for (int dy = 0; dy < 2; ++dy) {
#pragma unroll
        for (int dx = 0; dx < 2; ++dx) {
          float w = value * (dx ? fx : gx) * (dy ? fy : gy) * (dz ? fz : gz);
          int px = bx + dx, py = by + dy, pz = bz + dz;
          if (px < 0) px += V;   // JAX negative-index wrap
          if (py < 0) py += V;
          if (pz < 0) pz += V;
          if (px >= V || py >= V || pz >= V) continue;  // OOB dropped
          int lx = px - ox, ly = py - oy, lz = pz - oz;
          if ((unsigned)lx < (unsigned)TD && (unsigned)ly < (unsigned)TD &&
              (unsigned)lz < (unsigned)TD) {
            atomicAdd(&tl[lz * (TD * TD) + ly * TD + lx], w);
          } else {
            // wrapped-around corner: rare, direct device atomic into vol
            atomicAdd(vol + ((size_t)pz * V * V + (size_t)py * V + px), w);
          }
        }
      }
    }
  }
  __syncthreads();
  for (int j = threadIdx.x; j < TSIZE; j += 256) priv[(size_t)t * TPAD + j] = tl[j];
}

// ---------------- C: gather private tile blocks into the volume ----------------
__global__ __launch_bounds__(256) void k_gather(const float* __restrict__ priv,
                                                float* __restrict__ vol) {
  int idx = blockIdx.x * 256 + threadIdx.x;
  int x = idx & 127, y = (idx >> 7) & 127, z = idx >> 14;
  float s = vol[idx];  // wrapped-corner fallback contributions
  int txs[2] = {x >> 4, (x >> 4) - 1}, lxs[2] = {x & 15, 16};
  int tys[2] = {y >> 4, (y >> 4) - 1}, lys[2] = {y & 15, 16};
  int tzs[2] = {z >> 4, (z >> 4) - 1}, lzs[2] = {z & 15, 16};
  int nx = ((x & 15) == 0 && x > 0) ? 2 : 1;
  int ny = ((y & 15) == 0 && y > 0) ? 2 : 1;
  int nz = ((z & 15) == 0 && z > 0) ? 2 : 1;
  for (int iz = 0; iz < nz; ++iz)
    for (int iy = 0; iy < ny; ++iy)
      for (int ix = 0; ix < nx; ++ix) {
        int t = (tzs[iz] << 6) | (tys[iy] << 3) | txs[ix];
        s += priv[(size_t)t * TPAD + lzs[iz] * (TD * TD) + lys[iy] * TD + lxs[ix]];
      }
  vol[idx] = s;
}

// ---------------- fallback: direct scatter (if ws too small) ----------------
__global__ __launch_bounds__(256) void k_scatter(
    const int* __restrict__ inds, const float* __restrict__ refv,
    const float* __restrict__ W5, const float* __restrict__ b5,
    const float* __restrict__ x8_buf, float* __restrict__ vol, int N) {
  __shared__ float x8[8];
  if (threadIdx.x < 8) x8[threadIdx.x] = x8_buf[threadIdx.x];
  __syncthreads();
  int i = blockIdx.x * blockDim.x + threadIdx.x;
  if (i >= N) return;
  const size_t fourN = (size_t)4 * N;
  float4 o = *(const float4*)(b5 + (size_t)4 * i);
  float out0 = o.x, out1 = o.y, out2 = o.z, out3 = o.w;
#pragma unroll
  for (int k = 0; k < 8; ++k) {
    float xv = x8[k];
    float4 w = *(const float4*)(W5 + (size_t)k * fourN + (size_t)4 * i);
    out0 += xv * w.x; out1 += xv * w.y; out2 += xv * w.z; out3 += xv * w.w;
  }
  float value = refv[i] + out3;
  value = value > 0.f ? value : 0.f;
  int i0 = inds[3 * i], i1 = inds[3 * i + 1], i2 = inds[3 * i + 2];
  float cx = (((float)i2 - 64.0f) * 0.015625f + out0) * 64.0f + 64.0f;
  float cy = (((float)i1 - 64.0f) * 0.015625f + out1) * 64.0f + 64.0f;
  float cz = (((float)i0 - 64.0f) * 0.015625f + out2) * 64.0f + 64.0f;
  float bxf = floorf(cx), byf = floorf(cy), bzf = floorf(cz);
  int bx = (int)bxf, by = (int)byf, bz = (int)bzf;
  float fx = cx - bxf, fy = cy - byf, fz = cz - bzf;
  float gx = 1.f - fx, gy = 1.f - fy, gz = 1.f - fz;
#pragma unroll
  for (int dz = 0; dz < 2; ++dz)
#pragma unroll
    for (int dy = 0; dy < 2; ++dy)
#pragma unroll
      for (int dx = 0; dx < 2; ++dx) {
        float w = (dx ? fx : gx) * (dy ? fy : gy) * (dz ? fz : gz);
        int px = bx + dx, py = by + dy, pz = bz + dz;
        if (px < 0) px += V;
        if (py < 0) py += V;
        if (pz < 0) pz += V;
        if ((unsigned)px < (unsigned)V && (unsigned)py < (unsigned)V &&
            (unsigned)pz < (unsigned)V)
          atomicAdd(vol + ((size_t)pz * V * V + (size_t)py * V + px), value * w);
      }
}

extern "C" void kernel_launch(void* const* d_in, const int* in_sizes, int n_in,
                              void* d_out, int out_size, void* d_ws, size_t ws_size,
                              hipStream_t stream) {
  const int*   inds = (const int*)d_in[0];
  const float* refv = (const float*)d_in[1];
  const float* W0   = (const float*)d_in[2];
  const float* b0   = (const float*)d_in[3];
  const float* W1   = (const float*)d_in[4];
  const float* b1   = (const float*)d_in[5];
  const float* W2   = (const float*)d_in[6];
  const float* b2   = (const float*)d_in[7];
  const float* W3   = (const float*)d_in[8];
  const float* b3   = (const float*)d_in[9];
  const float* W4   = (const float*)d_in[10];
  const float* b4   = (const float*)d_in[11];
  const float* W5   = (const float*)d_in[12];
  const float* b5   = (const float*)d_in[13];

  int N = in_sizes[0] / 3;
  float* vol = (float*)d_out;
  char* w = (char*)d_ws;

  const int NB_R = 2048;  // reduce blocks
  // workspace layout (bytes)
  float*  x8       = (float*)(w + 0);            // 8 floats
  float*  partials = (float*)(w + 256);          // NB_R*8 floats = 64KB
  int*    gcnt     = (int*)(w + 131072);         // 512 ints
  float4* srt      = (float4*)(w + 262144);      // NTILES*CAP*16B = 32MB
  float*  priv     = (float*)(srt + (size_t)NTILES * CAP);  // NTILES*TPAD*4B = 10MB

  size_t needed = (size_t)262144 + (size_t)NTILES * CAP * 16 +
                  (size_t)NTILES * TPAD * 4;

  hipMemsetAsync(d_out, 0, (size_t)out_size * sizeof(float), stream);

  k_reduce_w0<<<NB_R, 256, 0, stream>>>(inds, W0, partials, 3 * N);
  k_mlp<<<1, 256, 0, stream>>>(partials, NB_R, b0, W1, b1, W2, b2, W3, b3, W4, b4, x8);

  if (ws_size >= needed) {
    hipMemsetAsync(gcnt, 0, NTILES * sizeof(int), stream);
    k_decode_scatter<<<(N + 255) / 256, 256, 0, stream>>>(inds, refv, W5, b5, x8,
                                                          srt, gcnt, N);
    k_tile<<<NTILES, 256, 0, stream>>>(srt, gcnt, priv, vol);
    k_gather<<<(V * V * V) / 256, 256, 0, stream>>>(priv, vol);
  } else {
    k_scatter<<<(N + 255) / 256, 256, 0, stream>>>(inds, refv, W5, b5, x8, vol, N);
  }
}

// Round 4
// 369.011 us; speedup vs baseline: 1.3847x; 1.3847x over previous
//
#include <hip/hip_runtime.h>
#include <hip/hip_bf16.h>

constexpr int V = 128;
constexpr int NTILES = 512;          // 8^3 tiles of 16^3
constexpr int TD = 17;               // tile cells per dim incl +1 halo
constexpr int TSIZE = TD * TD * TD;  // 4913
constexpr int TPAD = 5120;           // padded tile block (floats)
constexpr int NS = 16;               // counter/bucket stripes (kills line contention)
constexpr int CAPS = 256;            // capacity per (tile,stripe); mean ~61

// ---------------- Kernel 1: partial[b][8] = chunk of coords_flat @ W0 ----------------
__global__ __launch_bounds__(256) void k_reduce_w0(
    const int* __restrict__ inds, const float* __restrict__ W0,
    float* __restrict__ partials, int threeN) {
  float acc[8];
#pragma unroll
  for (int k = 0; k < 8; ++k) acc[k] = 0.f;

  int stride = gridDim.x * blockDim.x;
  for (int j = blockIdx.x * blockDim.x + threadIdx.x; j < threeN; j += stride) {
    int c = j % 3;
    float cval = ((float)inds[j + 2 - 2 * c] - 64.0f) * 0.015625f;
    const float4* w = (const float4*)(W0 + (size_t)j * 8);
    float4 a = w[0];
    float4 b = w[1];
    acc[0] += cval * a.x; acc[1] += cval * a.y;
    acc[2] += cval * a.z; acc[3] += cval * a.w;
    acc[4] += cval * b.x; acc[5] += cval * b.y;
    acc[6] += cval * b.z; acc[7] += cval * b.w;
  }

#pragma unroll
  for (int off = 32; off > 0; off >>= 1) {
#pragma unroll
    for (int k = 0; k < 8; ++k) acc[k] += __shfl_down(acc[k], off);
  }

  __shared__ float red[4][8];
  int wave = threadIdx.x >> 6;
  int lane = threadIdx.x & 63;
  if (lane == 0) {
#pragma unroll
    for (int k = 0; k < 8; ++k) red[wave][k] = acc[k];
  }
  __syncthreads();
  if (threadIdx.x < 8) {
    int k = threadIdx.x;
    partials[(size_t)blockIdx.x * 8 + k] = red[0][k] + red[1][k] + red[2][k] + red[3][k];
  }
}

// ---------------- Kernel 2: reduce partials + tiny MLP ----------------
__global__ __launch_bounds__(256) void k_mlp(
    const float* __restrict__ partials, int nb,
    const float* __restrict__ b0,
    const float* __restrict__ W1, const float* __restrict__ b1,
    const float* __restrict__ W2, const float* __restrict__ b2,
    const float* __restrict__ W3, const float* __restrict__ b3,
    const float* __restrict__ W4, const float* __restrict__ b4,
    float* __restrict__ x8_out) {
  __shared__ float red[256];
  __shared__ float accv[8];
  int tid = threadIdx.x;
  int k = tid & 7;
  float s = 0.f;
  for (int b = tid >> 3; b < nb; b += 32) s += partials[(size_t)b * 8 + k];
  red[tid] = s;
  __syncthreads();
  if (tid < 8) {
    float t = 0.f;
    for (int j = tid; j < 256; j += 8) t += red[j];
    accv[tid] = t;
  }
  __syncthreads();
  if (tid == 0) {
    float x[8];
#pragma unroll
    for (int kk = 0; kk < 8; ++kk) x[kk] = sinf(accv[kk] + b0[kk]);
    const float* Ws[4] = {W1, W2, W3, W4};
    const float* bs[4] = {b1, b2, b3, b4};
    for (int l = 0; l < 4; ++l) {
      float t[8];
#pragma unroll
      for (int kk = 0; kk < 8; ++kk) {
        float ss = bs[l][kk];
#pragma unroll
        for (int j = 0; j < 8; ++j) ss += x[j] * Ws[l][j * 8 + kk];
        t[kk] = ss;
      }
#pragma unroll
      for (int kk = 0; kk < 8; ++kk) x[kk] += sinf(t[kk]);
    }
#pragma unroll
    for (int kk = 0; kk < 8; ++kk) x8_out[kk] = x[kk];
  }
}

__device__ inline int tile_of(float cx, float cy, float cz) {
  int bx = (int)floorf(cx), by = (int)floorf(cy), bz = (int)floorf(cz);
  int tx = min(max(bx, 0), V - 1) >> 4;
  int ty = min(max(by, 0), V - 1) >> 4;
  int tz = min(max(bz, 0), V - 1) >> 4;
  return (tz << 6) | (ty << 3) | tx;
}

__device__ inline void scatter_direct(float* vol, float cx, float cy, float cz,
                                      float value) {
  float bxf = floorf(cx), byf = floorf(cy), bzf = floorf(cz);
  int bx = (int)bxf, by = (int)byf, bz = (int)bzf;
  float fx = cx - bxf, fy = cy - byf, fz = cz - bzf;
  float gx = 1.f - fx, gy = 1.f - fy, gz = 1.f - fz;
#pragma unroll
  for (int dz = 0; dz < 2; ++dz)
#pragma unroll
    for (int dy = 0; dy < 2; ++dy)
#pragma unroll
      for (int dx = 0; dx < 2; ++dx) {
        float w = value * (dx ? fx : gx) * (dy ? fy : gy) * (dz ? fz : gz);
        int px = bx + dx, py = by + dy, pz = bz + dz;
        if (px < 0) px += V;
        if (py < 0) py += V;
        if (pz < 0) pz += V;
        if ((unsigned)px < (unsigned)V && (unsigned)py < (unsigned)V &&
            (unsigned)pz < (unsigned)V)
          atomicAdd(vol + ((size_t)pz * V * V + (size_t)py * V + px), w);
      }
}

// ---------------- A: decode + striped bucket scatter ----------------
// cnt layout: cnt[(s*NTILES + t) * 16]  (each counter on its own 64B line)
// srt layout: srt[((s*NTILES + t) * CAPS + pos)]
__global__ __launch_bounds__(256) void k_decode_scatter(
    const int* __restrict__ inds, const float* __restrict__ refv,
    const float* __restrict__ W5, const float* __restrict__ b5,
    const float* __restrict__ x8_buf, float4* __restrict__ srt,
    int* __restrict__ cnt, float* __restrict__ vol, int N) {
  __shared__ float x8[8];
  if (threadIdx.x < 8) x8[threadIdx.x] = x8_buf[threadIdx.x];
  __syncthreads();

  int i = blockIdx.x * 256 + threadIdx.x;
  if (i >= N) return;

  const size_t fourN = (size_t)4 * N;
  float4 o = *(const float4*)(b5 + (size_t)4 * i);
  float out0 = o.x, out1 = o.y, out2 = o.z, out3 = o.w;
#pragma unroll
  for (int k = 0; k < 8; ++k) {
    float xv = x8[k];
    float4 w = *(const float4*)(W5 + (size_t)k * fourN + (size_t)4 * i);
    out0 += xv * w.x; out1 += xv * w.y; out2 += xv * w.z; out3 += xv * w.w;
  }
  float value = refv[i] + out3;
  value = value > 0.f ? value : 0.f;
  if (value <= 0.f) return;  // zero value contributes nothing

  int i0 = inds[3 * i], i1 = inds[3 * i + 1], i2 = inds[3 * i + 2];
  float cx = (((float)i2 - 64.0f) * 0.015625f + out0) * 64.0f + 64.0f;
  float cy = (((float)i1 - 64.0f) * 0.015625f + out1) * 64.0f + 64.0f;
  float cz = (((float)i0 - 64.0f) * 0.015625f + out2) * 64.0f + 64.0f;

  int t = tile_of(cx, cy, cz);
  int s = blockIdx.x & (NS - 1);
  int slot = s * NTILES + t;
  int pos = atomicAdd(&cnt[slot * 16], 1);
  if (pos < CAPS) {
    srt[(size_t)slot * CAPS + pos] = make_float4(cx, cy, cz, value);
  } else {
    scatter_direct(vol, cx, cy, cz, value);  // statistically never; correct anyway
  }
}

// ---------------- B: per-tile LDS scatter -> private tile blocks ----------------
__global__ __launch_bounds__(256) void k_tile(
    const float4* __restrict__ srt, const int* __restrict__ cnt,
    float* __restrict__ priv, float* __restrict__ vol) {
  __shared__ float tl[TSIZE];
  int t = blockIdx.x;
  int ox = (t & 7) << 4, oy = ((t >> 3) & 7) << 4, oz = (t >> 6) << 4;
  for (int j = threadIdx.x; j < TSIZE; j += 256) tl[j] = 0.f;
  __syncthreads();

  for (int s = 0; s < NS; ++s) {
    int slot = s * NTILES + t;
    int c = min(cnt[slot * 16], CAPS);
    const float4* base = srt + (size_t)slot * CAPS;
    for (int i = threadIdx.x; i < c; i += 256) {
      float4 r = base[i];
      float bxf = floorf(r.x), byf = floorf(r.y), bzf = floorf(r.z);
      int bx = (int)bxf, by = (int)byf, bz = (int)bzf;
      float fx = r.x - bxf, fy = r.y - byf, fz = r.z - bzf;
      float gx = 1.f - fx, gy = 1.f - fy, gz = 1.f - fz;
      float value = r.w;

#pragma unroll
      for (int dz = 0; dz < 2; ++dz) {
#pragma unroll
        for (int dy = 0; dy < 2; ++dy) {
#pragma unroll
          for (int dx = 0; dx < 2; ++dx) {
            float w = value * (dx ? fx : gx) * (dy ? fy : gy) * (dz ? fz : gz);
            int px = bx + dx, py = by + dy, pz = bz + dz;
            if (px < 0) px += V;   // JAX negative-index wrap
            if (py < 0) py += V;
            if (pz < 0) pz += V;
            if (px >= V || py >= V || pz >= V) continue;  // OOB dropped
            int lx = px - ox, ly = py - oy, lz = pz - oz;
            if ((unsigned)lx < (unsigned)TD && (unsigned)ly < (unsigned)TD &&
                (unsigned)lz < (unsigned)TD) {
              atomicAdd(&tl[lz * (TD * TD) + ly * TD + lx], w);
            } else {
              // wrapped-around corner: rare, direct device atomic into vol
              atomicAdd(vol + ((size_t)pz * V * V + (size_t)py * V + px), w);
            }
          }
        }
      }
    }
  }
  __syncthreads();
  for (int j = threadIdx.x; j < TSIZE; j += 256) priv[(size_t)t * TPAD + j] = tl[j];
}

// ---------------- C: gather private tile blocks into the volume ----------------
__global__ __launch_bounds__(256) void k_gather(const float* __restrict__ priv,
                                                float* __restrict__ vol) {
  int idx = blockIdx.x * 256 + threadIdx.x;
  int x = idx & 127, y = (idx >> 7) & 127, z = idx >> 14;
  float s = vol[idx];  // direct-atomic fallback contributions
  int txs[2] = {x >> 4, (x >> 4) - 1}, lxs[2] = {x & 15, 16};
  int tys[2] = {y >> 4, (y >> 4) - 1}, lys[2] = {y & 15, 16};
  int tzs[2] = {z >> 4, (z >> 4) - 1}, lzs[2] = {z & 15, 16};
  int nx = ((x & 15) == 0 && x > 0) ? 2 : 1;
  int ny = ((y & 15) == 0 && y > 0) ? 2 : 1;
  int nz = ((z & 15) == 0 && z > 0) ? 2 : 1;
  for (int iz = 0; iz < nz; ++iz)
    for (int iy = 0; iy < ny; ++iy)
      for (int ix = 0; ix < nx; ++ix) {
        int t = (tzs[iz] << 6) | (tys[iy] << 3) | txs[ix];
        s += priv[(size_t)t * TPAD + lzs[iz] * (TD * TD) + lys[iy] * TD + lxs[ix]];
      }
  vol[idx] = s;
}

// ---------------- fallback: direct scatter (if ws too small) ----------------
__global__ __launch_bounds__(256) void k_scatter(
    const int* __restrict__ inds, const float* __restrict__ refv,
    const float* __restrict__ W5, const float* __restrict__ b5,
    const float* __restrict__ x8_buf, float* __restrict__ vol, int N) {
  __shared__ float x8[8];
  if (threadIdx.x < 8) x8[threadIdx.x] = x8_buf[threadIdx.x];
  __syncthreads();
  int i = blockIdx.x * blockDim.x + threadIdx.x;
  if (i >= N) return;
  const size_t fourN = (size_t)4 * N;
  float4 o = *(const float4*)(b5 + (size_t)4 * i);
  float out0 = o.x, out1 = o.y, out2 = o.z, out3 = o.w;
#pragma unroll
  for (int k = 0; k < 8; ++k) {
    float xv = x8[k];
    float4 w = *(const float4*)(W5 + (size_t)k * fourN + (size_t)4 * i);
    out0 += xv * w.x; out1 += xv * w.y; out2 += xv * w.z; out3 += xv * w.w;
  }
  float value = refv[i] + out3;
  value = value > 0.f ? value : 0.f;
  int i0 = inds[3 * i], i1 = inds[3 * i + 1], i2 = inds[3 * i + 2];
  float cx = (((float)i2 - 64.0f) * 0.015625f + out0) * 64.0f + 64.0f;
  float cy = (((float)i1 - 64.0f) * 0.015625f + out1) * 64.0f + 64.0f;
  float cz = (((float)i0 - 64.0f) * 0.015625f + out2) * 64.0f + 64.0f;
  scatter_direct(vol, cx, cy, cz, value);
}

extern "C" void kernel_launch(void* const* d_in, const int* in_sizes, int n_in,
                              void* d_out, int out_size, void* d_ws, size_t ws_size,
                              hipStream_t stream) {
  const int*   inds = (const int*)d_in[0];
  const float* refv = (const float*)d_in[1];
  const float* W0   = (const float*)d_in[2];
  const float* b0   = (const float*)d_in[3];
  const float* W1   = (const float*)d_in[4];
  const float* b1   = (const float*)d_in[5];
  const float* W2   = (const float*)d_in[6];
  const float* b2   = (const float*)d_in[7];
  const float* W3   = (const float*)d_in[8];
  const float* b3   = (const float*)d_in[9];
  const float* W4   = (const float*)d_in[10];
  const float* b4   = (const float*)d_in[11];
  const float* W5   = (const float*)d_in[12];
  const float* b5   = (const float*)d_in[13];

  int N = in_sizes[0] / 3;
  float* vol = (float*)d_out;
  char* w = (char*)d_ws;

  const int NB_R = 2048;  // reduce blocks
  // workspace layout (bytes)
  float*  x8       = (float*)(w + 0);            // 8 floats
  float*  partials = (float*)(w + 256);          // NB_R*8 floats = 64KB
  int*    cnt      = (int*)(w + 131072);         // NS*NTILES*64B = 512KB
  float4* srt      = (float4*)(w + 1048576);     // NS*NTILES*CAPS*16B = 32MB
  float*  priv     = (float*)(srt + (size_t)NS * NTILES * CAPS);  // 10MB

  size_t needed = (size_t)1048576 + (size_t)NS * NTILES * CAPS * 16 +
                  (size_t)NTILES * TPAD * 4;

  hipMemsetAsync(d_out, 0, (size_t)out_size * sizeof(float), stream);

  k_reduce_w0<<<NB_R, 256, 0, stream>>>(inds, W0, partials, 3 * N);
  k_mlp<<<1, 256, 0, stream>>>(partials, NB_R, b0, W1, b1, W2, b2, W3, b3, W4, b4, x8);

  if (ws_size >= needed) {
    hipMemsetAsync(cnt, 0, (size_t)NS * NTILES * 64, stream);
    k_decode_scatter<<<(N + 255) / 256, 256, 0, stream>>>(inds, refv, W5, b5, x8,
                                                          srt, cnt, vol, N);
    k_tile<<<NTILES, 256, 0, stream>>>(srt, cnt, priv, vol);
    k_gather<<<(V * V * V) / 256, 256, 0, stream>>>(priv, vol);
  } else {
    k_scatter<<<(N + 255) / 256, 256, 0, stream>>>(inds, refv, W5, b5, x8, vol, N);
  }
}

// Round 5
// 362.297 us; speedup vs baseline: 1.4103x; 1.0185x over previous
//
#include <hip/hip_runtime.h>
#include <hip/hip_bf16.h>

constexpr int V = 128;
constexpr int NTILES = 512;          // 8^3 tiles of 16^3
constexpr int TD = 17;               // tile cells per dim incl +1 halo
constexpr int TSIZE = TD * TD * TD;  // 4913
constexpr int TPAD = 5120;           // padded tile block (floats)
constexpr int NS = 16;               // counter/bucket stripes (kills line contention)
constexpr int CAPS = 256;            // capacity per (tile,stripe); mean ~67
constexpr int CNT_INTS = NS * NTILES * 16;  // padded counters (one per 64B line)

// ---------------- Kernel 1: partial[b][8] = chunk of coords_flat @ W0 ----------------
// Also zeroes vol (8 MB) and cnt (512 KB) in its prologue: these stores hide
// under the 108 MB W0/inds fetch, removing two fill dispatches.
__global__ __launch_bounds__(256) void k_reduce_w0(
    const int* __restrict__ inds, const float* __restrict__ W0,
    float* __restrict__ partials, float4* __restrict__ vol4,
    int4* __restrict__ cnt4, int threeN) {
  int g = blockIdx.x * 256 + threadIdx.x;
  // zero vol: 2M floats = 524288 float4, grid is exactly 2048*256 = 524288
  vol4[g] = make_float4(0.f, 0.f, 0.f, 0.f);
  // zero cnt: 131072 ints = 32768 int4
  if (cnt4 && g < CNT_INTS / 4) cnt4[g] = make_int4(0, 0, 0, 0);

  float acc[8];
#pragma unroll
  for (int k = 0; k < 8; ++k) acc[k] = 0.f;

  int stride = gridDim.x * blockDim.x;
  for (int j = g; j < threeN; j += stride) {
    int c = j % 3;
    float cval = ((float)inds[j + 2 - 2 * c] - 64.0f) * 0.015625f;
    const float4* w = (const float4*)(W0 + (size_t)j * 8);
    float4 a = w[0];
    float4 b = w[1];
    acc[0] += cval * a.x; acc[1] += cval * a.y;
    acc[2] += cval * a.z; acc[3] += cval * a.w;
    acc[4] += cval * b.x; acc[5] += cval * b.y;
    acc[6] += cval * b.z; acc[7] += cval * b.w;
  }

#pragma unroll
  for (int off = 32; off > 0; off >>= 1) {
#pragma unroll
    for (int k = 0; k < 8; ++k) acc[k] += __shfl_down(acc[k], off);
  }

  __shared__ float red[4][8];
  int wave = threadIdx.x >> 6;
  int lane = threadIdx.x & 63;
  if (lane == 0) {
#pragma unroll
    for (int k = 0; k < 8; ++k) red[wave][k] = acc[k];
  }
  __syncthreads();
  if (threadIdx.x < 8) {
    int k = threadIdx.x;
    partials[(size_t)blockIdx.x * 8 + k] = red[0][k] + red[1][k] + red[2][k] + red[3][k];
  }
}

// ---------------- Kernel 2: reduce partials + tiny MLP ----------------
__global__ __launch_bounds__(256) void k_mlp(
    const float* __restrict__ partials, int nb,
    const float* __restrict__ b0,
    const float* __restrict__ W1, const float* __restrict__ b1,
    const float* __restrict__ W2, const float* __restrict__ b2,
    const float* __restrict__ W3, const float* __restrict__ b3,
    const float* __restrict__ W4, const float* __restrict__ b4,
    float* __restrict__ x8_out) {
  __shared__ float red[256];
  __shared__ float accv[8];
  int tid = threadIdx.x;
  int k = tid & 7;
  float s = 0.f;
  for (int b = tid >> 3; b < nb; b += 32) s += partials[(size_t)b * 8 + k];
  red[tid] = s;
  __syncthreads();
  if (tid < 8) {
    float t = 0.f;
    for (int j = tid; j < 256; j += 8) t += red[j];
    accv[tid] = t;
  }
  __syncthreads();
  if (tid == 0) {
    float x[8];
#pragma unroll
    for (int kk = 0; kk < 8; ++kk) x[kk] = sinf(accv[kk] + b0[kk]);
    const float* Ws[4] = {W1, W2, W3, W4};
    const float* bs[4] = {b1, b2, b3, b4};
    for (int l = 0; l < 4; ++l) {
      float t[8];
#pragma unroll
      for (int kk = 0; kk < 8; ++kk) {
        float ss = bs[l][kk];
#pragma unroll
        for (int j = 0; j < 8; ++j) ss += x[j] * Ws[l][j * 8 + kk];
        t[kk] = ss;
      }
#pragma unroll
      for (int kk = 0; kk < 8; ++kk) x[kk] += sinf(t[kk]);
    }
#pragma unroll
    for (int kk = 0; kk < 8; ++kk) x8_out[kk] = x[kk];
  }
}

__device__ inline int tile_of(float cx, float cy, float cz) {
  int bx = (int)floorf(cx), by = (int)floorf(cy), bz = (int)floorf(cz);
  int tx = min(max(bx, 0), V - 1) >> 4;
  int ty = min(max(by, 0), V - 1) >> 4;
  int tz = min(max(bz, 0), V - 1) >> 4;
  return (tz << 6) | (ty << 3) | tx;
}

__device__ inline void scatter_direct(float* vol, float cx, float cy, float cz,
                                      float value) {
  float bxf = floorf(cx), byf = floorf(cy), bzf = floorf(cz);
  int bx = (int)bxf, by = (int)byf, bz = (int)bzf;
  float fx = cx - bxf, fy = cy - byf, fz = cz - bzf;
  float gx = 1.f - fx, gy = 1.f - fy, gz = 1.f - fz;
#pragma unroll
  for (int dz = 0; dz < 2; ++dz)
#pragma unroll
    for (int dy = 0; dy < 2; ++dy)
#pragma unroll
      for (int dx = 0; dx < 2; ++dx) {
        float w = value * (dx ? fx : gx) * (dy ? fy : gy) * (dz ? fz : gz);
        int px = bx + dx, py = by + dy, pz = bz + dz;
        if (px < 0) px += V;
        if (py < 0) py += V;
        if (pz < 0) pz += V;
        if ((unsigned)px < (unsigned)V && (unsigned)py < (unsigned)V &&
            (unsigned)pz < (unsigned)V)
          atomicAdd(vol + ((size_t)pz * V * V + (size_t)py * V + px), w);
      }
}

// ---------------- A: decode + striped bucket scatter ----------------
// cnt layout: cnt[(s*NTILES + t) * 16]  (each counter on its own 64B line)
// srt layout: srt[((s*NTILES + t) * CAPS + pos)]
__global__ __launch_bounds__(256) void k_decode_scatter(
    const int* __restrict__ inds, const float* __restrict__ refv,
    const float* __restrict__ W5, const float* __restrict__ b5,
    const float* __restrict__ x8_buf, float4* __restrict__ srt,
    int* __restrict__ cnt, float* __restrict__ vol, int N) {
  __shared__ float x8[8];
  if (threadIdx.x < 8) x8[threadIdx.x] = x8_buf[threadIdx.x];
  __syncthreads();

  int i = blockIdx.x * 256 + threadIdx.x;
  if (i >= N) return;

  const size_t fourN = (size_t)4 * N;
  float4 o = *(const float4*)(b5 + (size_t)4 * i);
  float out0 = o.x, out1 = o.y, out2 = o.z, out3 = o.w;
#pragma unroll
  for (int k = 0; k < 8; ++k) {
    float xv = x8[k];
    float4 w = *(const float4*)(W5 + (size_t)k * fourN + (size_t)4 * i);
    out0 += xv * w.x; out1 += xv * w.y; out2 += xv * w.z; out3 += xv * w.w;
  }
  float value = refv[i] + out3;
  value = value > 0.f ? value : 0.f;
  if (value <= 0.f) return;  // zero value contributes nothing

  int i0 = inds[3 * i], i1 = inds[3 * i + 1], i2 = inds[3 * i + 2];
  float cx = (((float)i2 - 64.0f) * 0.015625f + out0) * 64.0f + 64.0f;
  float cy = (((float)i1 - 64.0f) * 0.015625f + out1) * 64.0f + 64.0f;
  float cz = (((float)i0 - 64.0f) * 0.015625f + out2) * 64.0f + 64.0f;

  int t = tile_of(cx, cy, cz);
  int s = blockIdx.x & (NS - 1);
  int slot = s * NTILES + t;
  int pos = atomicAdd(&cnt[slot * 16], 1);
  if (pos < CAPS) {
    srt[(size_t)slot * CAPS + pos] = make_float4(cx, cy, cz, value);
  } else {
    scatter_direct(vol, cx, cy, cz, value);  // statistically never; correct anyway
  }
}

// ---------------- B: per-tile LDS scatter -> private tile blocks ----------------
__global__ __launch_bounds__(256) void k_tile(
    const float4* __restrict__ srt, const int* __restrict__ cnt,
    float* __restrict__ priv, float* __restrict__ vol) {
  __shared__ float tl[TSIZE];
  int t = blockIdx.x;
  int ox = (t & 7) << 4, oy = ((t >> 3) & 7) << 4, oz = (t >> 6) << 4;
  for (int j = threadIdx.x; j < TSIZE; j += 256) tl[j] = 0.f;
  __syncthreads();

  for (int s = 0; s < NS; ++s) {
    int slot = s * NTILES + t;
    int c = min(cnt[slot * 16], CAPS);
    const float4* base = srt + (size_t)slot * CAPS;
    for (int i = threadIdx.x; i < c; i += 256) {
      float4 r = base[i];
      float bxf = floorf(r.x), byf = floorf(r.y), bzf = floorf(r.z);
      int bx = (int)bxf, by = (int)byf, bz = (int)bzf;
      float fx = r.x - bxf, fy = r.y - byf, fz = r.z - bzf;
      float gx = 1.f - fx, gy = 1.f - fy, gz = 1.f - fz;
      float value = r.w;

#pragma unroll
      for (int dz = 0; dz < 2; ++dz) {
#pragma unroll
        for (int dy = 0; dy < 2; ++dy) {
#pragma unroll
          for (int dx = 0; dx < 2; ++dx) {
            float w = value * (dx ? fx : gx) * (dy ? fy : gy) * (dz ? fz : gz);
            int px = bx + dx, py = by + dy, pz = bz + dz;
            if (px < 0) px += V;   // JAX negative-index wrap
            if (py < 0) py += V;
            if (pz < 0) pz += V;
            if (px >= V || py >= V || pz >= V) continue;  // OOB dropped
            int lx = px - ox, ly = py - oy, lz = pz - oz;
            if ((unsigned)lx < (unsigned)TD && (unsigned)ly < (unsigned)TD &&
                (unsigned)lz < (unsigned)TD) {
              atomicAdd(&tl[lz * (TD * TD) + ly * TD + lx], w);
            } else {
              // wrapped-around corner: rare, direct device atomic into vol
              atomicAdd(vol + ((size_t)pz * V * V + (size_t)py * V + px), w);
            }
          }
        }
      }
    }
  }
  __syncthreads();
  for (int j = threadIdx.x; j < TSIZE; j += 256) priv[(size_t)t * TPAD + j] = tl[j];
}

// ---------------- C: gather private tile blocks into the volume ----------------
__global__ __launch_bounds__(256) void k_gather(const float* __restrict__ priv,
                                                float* __restrict__ vol) {
  int idx = blockIdx.x * 256 + threadIdx.x;
  int x = idx & 127, y = (idx >> 7) & 127, z = idx >> 14;
  float s = vol[idx];  // direct-atomic fallback contributions
  int txs[2] = {x >> 4, (x >> 4) - 1}, lxs[2] = {x & 15, 16};
  int tys[2] = {y >> 4, (y >> 4) - 1}, lys[2] = {y & 15, 16};
  int tzs[2] = {z >> 4, (z >> 4) - 1}, lzs[2] = {z & 15, 16};
  int nx = ((x & 15) == 0 && x > 0) ? 2 : 1;
  int ny = ((y & 15) == 0 && y > 0) ? 2 : 1;
  int nz = ((z & 15) == 0 && z > 0) ? 2 : 1;
  for (int iz = 0; iz < nz; ++iz)
    for (int iy = 0; iy < ny; ++iy)
      for (int ix = 0; ix < nx; ++ix) {
        int t = (tzs[iz] << 6) | (tys[iy] << 3) | txs[ix];
        s += priv[(size_t)t * TPAD + lzs[iz] * (TD * TD) + lys[iy] * TD + lxs[ix]];
      }
  vol[idx] = s;
}

// ---------------- fallback: direct scatter (if ws too small) ----------------
__global__ __launch_bounds__(256) void k_scatter(
    const int* __restrict__ inds, const float* __restrict__ refv,
    const float* __restrict__ W5, const float* __restrict__ b5,
    const float* __restrict__ x8_buf, float* __restrict__ vol, int N) {
  __shared__ float x8[8];
  if (threadIdx.x < 8) x8[threadIdx.x] = x8_buf[threadIdx.x];
  __syncthreads();
  int i = blockIdx.x * blockDim.x + threadIdx.x;
  if (i >= N) return;
  const size_t fourN = (size_t)4 * N;
  float4 o = *(const float4*)(b5 + (size_t)4 * i);
  float out0 = o.x, out1 = o.y, out2 = o.z, out3 = o.w;
#pragma unroll
  for (int k = 0; k < 8; ++k) {
    float xv = x8[k];
    float4 w = *(const float4*)(W5 + (size_t)k * fourN + (size_t)4 * i);
    out0 += xv * w.x; out1 += xv * w.y; out2 += xv * w.z; out3 += xv * w.w;
  }
  float value = refv[i] + out3;
  value = value > 0.f ? value : 0.f;
  int i0 = inds[3 * i], i1 = inds[3 * i + 1], i2 = inds[3 * i + 2];
  float cx = (((float)i2 - 64.0f) * 0.015625f + out0) * 64.0f + 64.0f;
  float cy = (((float)i1 - 64.0f) * 0.015625f + out1) * 64.0f + 64.0f;
  float cz = (((float)i0 - 64.0f) * 0.015625f + out2) * 64.0f + 64.0f;
  scatter_direct(vol, cx, cy, cz, value);
}

extern "C" void kernel_launch(void* const* d_in, const int* in_sizes, int n_in,
                              void* d_out, int out_size, void* d_ws, size_t ws_size,
                              hipStream_t stream) {
  const int*   inds = (const int*)d_in[0];
  const float* refv = (const float*)d_in[1];
  const float* W0   = (const float*)d_in[2];
  const float* b0   = (const float*)d_in[3];
  const float* W1   = (const float*)d_in[4];
  const float* b1   = (const float*)d_in[5];
  const float* W2   = (const float*)d_in[6];
  const float* b2   = (const float*)d_in[7];
  const float* W3   = (const float*)d_in[8];
  const float* b3   = (const float*)d_in[9];
  const float* W4   = (const float*)d_in[10];
  const float* b4   = (const float*)d_in[11];
  const float* W5   = (const float*)d_in[12];
  const float* b5   = (const float*)d_in[13];

  int N = in_sizes[0] / 3;
  float* vol = (float*)d_out;
  char* w = (char*)d_ws;

  const int NB_R = 2048;  // reduce blocks; grid covers vol zeroing exactly
  // workspace layout (bytes)
  float*  x8       = (float*)(w + 0);            // 8 floats
  float*  partials = (float*)(w + 256);          // NB_R*8 floats = 64KB
  int*    cnt      = (int*)(w + 131072);         // NS*NTILES*64B = 512KB
  float4* srt      = (float4*)(w + 1048576);     // NS*NTILES*CAPS*16B = 32MB
  float*  priv     = (float*)(srt + (size_t)NS * NTILES * CAPS);  // 10MB

  size_t needed = (size_t)1048576 + (size_t)NS * NTILES * CAPS * 16 +
                  (size_t)NTILES * TPAD * 4;

  if (ws_size >= needed) {
    // k_reduce_w0 zeroes vol + cnt in its prologue (hides under W0 fetch)
    k_reduce_w0<<<NB_R, 256, 0, stream>>>(inds, W0, partials, (float4*)vol,
                                          (int4*)cnt, 3 * N);
    k_mlp<<<1, 256, 0, stream>>>(partials, NB_R, b0, W1, b1, W2, b2, W3, b3, W4, b4, x8);
    k_decode_scatter<<<(N + 255) / 256, 256, 0, stream>>>(inds, refv, W5, b5, x8,
                                                          srt, cnt, vol, N);
    k_tile<<<NTILES, 256, 0, stream>>>(srt, cnt, priv, vol);
    k_gather<<<(V * V * V) / 256, 256, 0, stream>>>(priv, vol);
  } else {
    hipMemsetAsync(d_out, 0, (size_t)out_size * sizeof(float), stream);
    k_reduce_w0<<<NB_R, 256, 0, stream>>>(inds, W0, partials, (float4*)vol,
                                          (int4*)nullptr, 3 * N);
    k_mlp<<<1, 256, 0, stream>>>(partials, NB_R, b0, W1, b1, W2, b2, W3, b3, W4, b4, x8);
    k_scatter<<<(N + 255) / 256, 256, 0, stream>>>(inds, refv, W5, b5, x8, vol, N);
  }
}